// Round 3
// baseline (260.899 us; speedup 1.0000x reference)
//
#include <hip/hip_runtime.h>
#include <stdint.h>

#pragma clang fp contract(off)

#define NBOX 8000      // 5x40x40 + 5x80x80
#define NFAST 896      // fast path cap: W<=14, tri mask <= 6720 u64 = 52.5 KB LDS
#define WMAX 14
typedef unsigned long long u64;

// Single-workgroup fused kernel: decode -> compact -> bitonic sort -> IoU bitmask
// -> monotone greedy scan -> write. One dispatch, no memset, counter in LDS.
__global__ __launch_bounds__(1024) void k_all(
    const float* __restrict__ outs0, const float* __restrict__ outs1,
    float* __restrict__ out,
    float4* __restrict__ wsBox,      // [8192] decoded xyxy by original idx g
    u64*    __restrict__ wsKeys,     // [8192] mirror of keys (fallback)
    float* __restrict__ ssc, float* __restrict__ sx1, float* __restrict__ sy1,
    float* __restrict__ sx2, float* __restrict__ sy2, float* __restrict__ sar)
{
    __shared__ u64 buf[6720];        // phase B/C: keys[0..1024); phase D/E: tri mask
    __shared__ u64 keptW[16];
    __shared__ int sN;
    const int tid = threadIdx.x;
    if (tid == 0) sN = 0;
    __syncthreads();

    // ---------------- Phase A: zero output, decode, collect valid ----------------
    float4* out4 = (float4*)out;     // 40000 f32 = 10000 float4
    #pragma unroll
    for (int i = 0; i < 10; ++i) {
        int idx = tid + i * 1024;
        if (idx < 10000) out4[idx] = make_float4(0.f, 0.f, 0.f, 0.f);
    }
    #pragma unroll
    for (int kk = 0; kk < 8; ++kk) {
        int g = tid + kk * 1024;
        if (g < NBOX) {
            const float* src; int local, i, j; float xps, yps; int pp;
            if (g < 1600) { src = outs0; local = g;        i = local/40; j = local - i*40; xps=16.f; yps=12.f; pp=1600; }
            else          { src = outs1; local = g - 1600; i = local/80; j = local - i*80; xps= 8.f; yps= 6.f; pp=6400; }
            float prob = src[local];
            if (prob > 0.9f) {
                float b1 = src[pp + local], b2 = src[2*pp + local];
                float b3 = src[3*pp + local], b4 = src[4*pp + local];
                // reference: ROW idx i scales x (ii[:,None]); COL idx j scales y
                float c1 = b1*xps + (float)i*xps;
                float c2 = b2*yps + (float)j*yps;
                float X1 = rintf(c1), Y1 = rintf(c2);
                float X2 = rintf(b3*640.0f + c1), Y2 = rintf(b4*480.0f + c2);
                int pos = atomicAdd(&sN, 1);
                unsigned u = __float_as_uint(prob);
                u ^= (u & 0x80000000u) ? 0xFFFFFFFFu : 0x80000000u;  // monotone map
                u64 key = ((u64)(~u) << 32) | (unsigned)g;  // asc = desc score, asc g
                if (pos < 1024) buf[pos] = key;
                wsKeys[pos] = key;
                wsBox[g] = make_float4(X1, Y1, X2, Y2);
            }
        }
    }
    __syncthreads();
    const int n = sN;

    if (n <= NFAST) {
        const int W = (n + 63) >> 6;
        // ---------------- Phase B: pad + bitonic sort (m=1024) ----------------
        if (tid >= n) buf[tid] = ~0ULL;
        __syncthreads();
        for (int k = 2; k <= 1024; k <<= 1) {
            for (int j = k >> 1; j > 0; j >>= 1) {
                int ixj = tid ^ j;
                if (ixj > tid) {
                    u64 a = buf[tid], b = buf[ixj];
                    bool up = ((tid & k) == 0);
                    if ((a > b) == up) { buf[tid] = b; buf[ixj] = a; }
                }
                __syncthreads();
            }
        }
        // ---------------- Phase C: sorted SoA to global ws ----------------
        if (tid < n) {
            u64 key = buf[tid];
            unsigned g = (unsigned)key;
            unsigned u = ~(unsigned)(key >> 32);
            float score = __uint_as_float(u ^ 0x80000000u);
            float4 bx = wsBox[g];
            ssc[tid] = score; sx1[tid] = bx.x; sy1[tid] = bx.y;
            sx2[tid] = bx.z;  sy2[tid] = bx.w;
            sar[tid] = (bx.z - bx.x) * (bx.w - bx.y);
        }
        __syncthreads();   // global writes visible workgroup-wide

        // ------- Phase D: tri mask, col-parallel (lane=col, ballot->word) -------
        // job = (row-quad rq, word slot k); 4 rows share coalesced column loads.
        {
            int wv = tid >> 6, lane = tid & 63;
            int nq = (n + 3) >> 2;
            int jobsFlat = nq * WMAX;
            for (int jb = wv; jb < jobsFlat; jb += 16) {
                int rq = jb / WMAX, k = jb - rq * WMAX;
                int r0 = rq << 2;
                int a = r0 >> 6;
                int w = a + k;
                if (w >= W) continue;
                int c = (w << 6) + lane;
                bool cv = c < n;
                int cc = cv ? c : 0;
                float cx1 = sx1[cc], cy1 = sy1[cc], cx2 = sx2[cc], cy2 = sy2[cc], car = sar[cc];
                u64 wb0 = 0, wb1 = 0, wb2 = 0, wb3 = 0;
                #pragma unroll
                for (int q = 0; q < 4; ++q) {
                    int r = r0 + q;
                    int rr = (r < n) ? r : 0;
                    float rx1 = sx1[rr], ry1 = sy1[rr], rx2 = sx2[rr], ry2 = sy2[rr], rar = sar[rr];
                    float iw = fminf(rx2, cx2) - fmaxf(rx1, cx1); iw = fmaxf(iw, 0.f);
                    float ih = fminf(ry2, cy2) - fmaxf(ry1, cy1); ih = fmaxf(ih, 0.f);
                    float inter = iw * ih;
                    float uni = rar + car - inter;
                    bool sup = cv && (uni > 0.f) && (inter > 0.5f * uni);  // exact: ints < 2^24
                    u64 bal = __ballot(sup);
                    if (q == 0) wb0 = bal; else if (q == 1) wb1 = bal;
                    else if (q == 2) wb2 = bal; else wb3 = bal;
                }
                if (lane < 4) {
                    int r = r0 + lane;
                    if (r < n) {
                        u64 word = (lane == 0) ? wb0 : (lane == 1) ? wb1 : (lane == 2) ? wb2 : wb3;
                        int b = r & 63;
                        if (w == a) {   // diagonal word: clear cols <= r
                            u64 low = (b == 63) ? ~0ULL : ((1ULL << (b + 1)) - 1);
                            word &= ~low;
                        }
                        int off = 64 * (a * W - (a * (a - 1)) / 2) + b * (W - a) + (w - a);
                        buf[off] = word;
                    }
                }
            }
        }
        __syncthreads();

        // ------- Phase E: monotone greedy scan, wave 0, no cross-lane in loop -------
        if (tid < 64) {
            int lane = tid;
            u64 fut = 0;
            if (lane < W) {
                int cnt = n - (lane << 6);
                fut = (cnt >= 64) ? ~0ULL : ((1ULL << cnt) - 1);
            }
            u64 keptLocal = 0;
            int cw = 0;
            u64 cur = (n >= 64) ? ~0ULL : ((n > 0) ? ((1ULL << n) - 1) : 0ULL);
            int base = 0;        // 64*(cw*W - cw*(cw-1)/2)
            int Wa = W;          // W - cw
            while (true) {
                if (cur == 0) {
                    u64 m = __ballot(fut != 0 && lane > cw);
                    if (m == 0) break;
                    int ncw = (int)__builtin_ctzll(m);
                    cur = __shfl(fut, ncw);
                    base = 64 * (ncw * W - (ncw * (ncw - 1)) / 2);
                    Wa = W - ncw;
                    cw = ncw;
                    continue;
                }
                int b = (int)__builtin_ctzll(cur);          // kept box i = 64*cw + b
                if (lane == cw) keptLocal |= (1ULL << b);
                int off = base + b * Wa;
                u64 rwa = buf[off];                          // word a: uniform -> broadcast
                u64 rw = 0;
                if (lane >= cw && lane < W) rw = buf[off + (lane - cw)];
                fut &= ~rw;                                  // suppress future words
                cur = (cur & (cur - 1)) & ~rwa;              // clear i + same-word kills
            }
            if (lane < 16) keptW[lane] = keptLocal;
        }
        __syncthreads();

        // ---------------- Phase F: write kept rows ----------------
        if (tid < n) {
            if ((keptW[tid >> 6] >> (tid & 63)) & 1ULL) {
                float x1 = sx1[tid], y1 = sy1[tid], x2 = sx2[tid], y2 = sy2[tid];
                out[5*tid+0] = ssc[tid];
                out[5*tid+1] = x1; out[5*tid+2] = y1;
                out[5*tid+3] = x2 - x1; out[5*tid+4] = y2 - y1;
            }
        }
    } else {
        // ============ correctness-only fallback (n > NFAST; never taken) ============
        // rank-sort via global keys (unique keys: low bits = g)
        for (int p = tid; p < n; p += 1024) {
            u64 kp = wsKeys[p];
            int rank = 0;
            for (int q = 0; q < n; ++q) rank += (wsKeys[q] < kp) ? 1 : 0;
            unsigned g = (unsigned)kp;
            unsigned u = ~(unsigned)(kp >> 32);
            float score = __uint_as_float(u ^ 0x80000000u);
            float4 bx = wsBox[g];
            ssc[rank] = score; sx1[rank] = bx.x; sy1[rank] = bx.y;
            sx2[rank] = bx.z;  sy2[rank] = bx.w;
            sar[rank] = (bx.z - bx.x) * (bx.w - bx.y);
        }
        __syncthreads();
        // kept-list arrays overlay wsBox+wsKeys region (dead after rank phase)
        float* KX1 = (float*)wsBox;
        float* KY1 = KX1 + 8192;
        float* KX2 = KX1 + 2 * 8192;
        float* KY2 = KX1 + 3 * 8192;
        float* KAR = KX1 + 4 * 8192;
        if (tid < 64) {
            int lane = tid;
            int kc = 0;
            for (int base2 = 0; base2 < n; base2 += 64) {
                int p = base2 + lane;
                bool in = p < n;
                float mx1=0.f,my1=0.f,mx2=0.f,my2=0.f,mar=0.f,msc=0.f;
                if (in) { mx1=sx1[p]; my1=sy1[p]; mx2=sx2[p]; my2=sy2[p]; mar=sar[p]; msc=ssc[p]; }
                bool dead = !in;
                for (int k = 0; k < kc; ++k) {
                    float iw = fminf(mx2, KX2[k]) - fmaxf(mx1, KX1[k]); iw = fmaxf(iw, 0.f);
                    float ih = fminf(my2, KY2[k]) - fmaxf(my1, KY1[k]); ih = fmaxf(ih, 0.f);
                    float inter = iw*ih;
                    float uni = mar + KAR[k] - inter;
                    if (uni > 0.f && inter > 0.5f*uni) dead = true;
                }
                u64 scan = __ballot(!dead);
                while (scan) {
                    int t = (int)__builtin_ctzll(scan);
                    scan &= scan - 1;
                    float tx1=__shfl(mx1,t), ty1=__shfl(my1,t), tx2=__shfl(mx2,t),
                          ty2=__shfl(my2,t), tar=__shfl(mar,t);
                    if (lane == t) {
                        KX1[kc]=mx1; KY1[kc]=my1; KX2[kc]=mx2; KY2[kc]=my2; KAR[kc]=mar;
                        out[5*p+0]=msc; out[5*p+1]=mx1; out[5*p+2]=my1;
                        out[5*p+3]=mx2-mx1; out[5*p+4]=my2-my1;
                    }
                    __threadfence();   // order kept-list stores before later loads
                    kc++;
                    bool kill = false;
                    if (!dead && lane > t) {
                        float iw = fminf(mx2,tx2) - fmaxf(mx1,tx1); iw = fmaxf(iw,0.f);
                        float ih = fminf(my2,ty2) - fmaxf(my1,ty1); ih = fmaxf(ih,0.f);
                        float inter = iw*ih;
                        float uni = mar + tar - inter;
                        kill = (uni > 0.f) && (inter > 0.5f*uni);
                    }
                    dead = dead || kill;
                    scan &= ~__ballot(dead);
                }
            }
        }
    }
}

extern "C" void kernel_launch(void* const* d_in, const int* in_sizes, int n_in,
                              void* d_out, int out_size, void* d_ws, size_t ws_size,
                              hipStream_t stream) {
    const float* outs0 = (const float*)d_in[0];
    const float* outs1 = (const float*)d_in[1];
    float* out = (float*)d_out;
    char* ws = (char*)d_ws;
    size_t o = 0;
    float4* wsBox = (float4*)(ws + o); o += (size_t)8192 * 16;   // 128 KB
    u64*    wsKeys = (u64*)(ws + o);   o += (size_t)8192 * 8;    // 64 KB
    float* ssc = (float*)(ws + o); o += (size_t)8192 * 4;
    float* sx1 = (float*)(ws + o); o += (size_t)8192 * 4;
    float* sy1 = (float*)(ws + o); o += (size_t)8192 * 4;
    float* sx2 = (float*)(ws + o); o += (size_t)8192 * 4;
    float* sy2 = (float*)(ws + o); o += (size_t)8192 * 4;
    float* sar = (float*)(ws + o); o += (size_t)8192 * 4;        // total ~393 KB

    hipLaunchKernelGGL(k_all, dim3(1), dim3(1024), 0, stream,
                       outs0, outs1, out, wsBox, wsKeys,
                       ssc, sx1, sy1, sx2, sy2, sar);
}

// Round 4
// 186.874 us; speedup vs baseline: 1.3961x; 1.3961x over previous
//
#include <hip/hip_runtime.h>
#include <stdint.h>

#pragma clang fp contract(off)

#define NBOX 8000      // 5x40x40 + 5x80x80
#define NFAST 896      // fast path cap: W<=14, tri mask = 6720 u64 = 52.5 KB LDS
typedef unsigned long long u64;

// Single-workgroup fused kernel. All hot phases LDS/VALU-resident:
// decode -> compact(LDS keys) -> bitonic sort(LDS) -> int boxes to LDS ->
// tri IoU bitmask (row-regs, LDS cols) -> register-diag greedy scan -> write.
__global__ __launch_bounds__(1024) void k_all(
    const float* __restrict__ outs0, const float* __restrict__ outs1,
    float* __restrict__ out,
    float4* __restrict__ wsBox,      // [8192] decoded xyxy by original idx g
    u64*    __restrict__ wsKeys,     // [8192] compacted keys (fallback path)
    u64*    __restrict__ sKeysG,     // [1024] sorted keys (fast path, for scores)
    float* __restrict__ ssc, float* __restrict__ sx1, float* __restrict__ sy1,
    float* __restrict__ sx2, float* __restrict__ sy2, float* __restrict__ sar)
{
    __shared__ u64 buf[6720];        // sort keys (first 1024) then tri mask; 52.5 KB
    __shared__ ushort4 sbox[NFAST];  // sorted int boxes; 7 KB
    __shared__ int sarea[NFAST];     // int areas; 3.5 KB
    __shared__ u64 keptW[16];
    __shared__ int sN;
    const int tid = threadIdx.x;
    if (tid == 0) sN = 0;
    if (tid < 16) keptW[tid] = 0;
    __syncthreads();

    // ---------------- Phase A: zero output, decode, compact ----------------
    float4* out4 = (float4*)out;     // 40000 f32 = 10000 float4
    #pragma unroll
    for (int i = 0; i < 10; ++i) {
        int idx = tid + i * 1024;
        if (idx < 10000) out4[idx] = make_float4(0.f, 0.f, 0.f, 0.f);
    }
    #pragma unroll
    for (int kk = 0; kk < 8; ++kk) {
        int g = tid + kk * 1024;
        if (g < NBOX) {
            const float* src; int local, i, j; float xps, yps; int pp;
            if (g < 1600) { src = outs0; local = g;        i = local/40; j = local - i*40; xps=16.f; yps=12.f; pp=1600; }
            else          { src = outs1; local = g - 1600; i = local/80; j = local - i*80; xps= 8.f; yps= 6.f; pp=6400; }
            float prob = src[local];
            if (prob > 0.9f) {
                float b1 = src[pp + local], b2 = src[2*pp + local];
                float b3 = src[3*pp + local], b4 = src[4*pp + local];
                // reference: ROW idx i scales x (ii[:,None]); COL idx j scales y
                float c1 = b1*xps + (float)i*xps;
                float c2 = b2*yps + (float)j*yps;
                float X1 = rintf(c1), Y1 = rintf(c2);
                float X2 = rintf(b3*640.0f + c1), Y2 = rintf(b4*480.0f + c2);
                int pos = atomicAdd(&sN, 1);
                unsigned u = __float_as_uint(prob);
                u ^= (u & 0x80000000u) ? 0xFFFFFFFFu : 0x80000000u;  // monotone map
                u64 key = ((u64)(~u) << 32) | (unsigned)g;  // asc = desc score, asc g
                if (pos < 1024) buf[pos] = key;
                wsKeys[pos] = key;
                wsBox[g] = make_float4(X1, Y1, X2, Y2);
            }
        }
    }
    __syncthreads();
    const int n = sN;

    if (n <= NFAST) {
        const int W = (n + 63) >> 6;
        // ---------------- Phase B: pad + bitonic sort (m=1024) ----------------
        if (tid >= n) buf[tid] = ~0ULL;
        __syncthreads();
        for (int k = 2; k <= 1024; k <<= 1) {
            for (int j = k >> 1; j > 0; j >>= 1) {
                int ixj = tid ^ j;
                if (ixj > tid) {
                    u64 a = buf[tid], b = buf[ixj];
                    bool up = ((tid & k) == 0);
                    if ((a > b) == up) { buf[tid] = b; buf[ixj] = a; }
                }
                __syncthreads();
            }
        }
        // ------- Phase C: gather boxes by sorted order into LDS as ints -------
        int mx1i=0, my1i=0, mx2i=0, my2i=0, mari=0;  // keep own row in regs for F
        if (tid < n) {
            u64 key = buf[tid];
            unsigned g = (unsigned)key;
            float4 bx = wsBox[g];
            mx1i = (int)bx.x; my1i = (int)bx.y; mx2i = (int)bx.z; my2i = (int)bx.w;
            mari = (mx2i - mx1i) * (my2i - my1i);
            sbox[tid] = make_ushort4((ushort)mx1i, (ushort)my1i, (ushort)mx2i, (ushort)my2i);
            sarea[tid] = mari;
            sKeysG[tid] = key;
        }
        __syncthreads();   // buf keys fully consumed; sbox/sarea visible

        // ------- Phase D: tri mask; 4 rows in regs, cols via LDS -------
        {
            int wv = tid >> 6, lane = tid & 63;
            int nq = (n + 3) >> 2;
            for (int rq = wv; rq < nq; rq += 16) {
                int r0 = rq << 2;
                int a = r0 >> 6;
                int rowBase = 64 * (a * W - (a * (a - 1)) / 2);
                int Wa = W - a;
                int rr0 = r0, rr1 = min(r0+1, n-1), rr2 = min(r0+2, n-1), rr3 = min(r0+3, n-1);
                ushort4 rb0 = sbox[rr0], rb1 = sbox[rr1], rb2 = sbox[rr2], rb3 = sbox[rr3];
                int ra0 = sarea[rr0], ra1 = sarea[rr1], ra2 = sarea[rr2], ra3 = sarea[rr3];
                for (int k = 0; k < Wa; ++k) {
                    int wcol = a + k;
                    int c = (wcol << 6) + lane;
                    bool cv = c < n;
                    int cc = cv ? c : (n - 1);
                    ushort4 cb = sbox[cc];
                    int car = sarea[cc];
                    int cx1 = cb.x, cy1 = cb.y, cx2 = cb.z, cy2 = cb.w;
                    u64 wb0, wb1, wb2, wb3;
                    {
                        int iw = min((int)rb0.z, cx2) - max((int)rb0.x, cx1); iw = max(iw, 0);
                        int ih = min((int)rb0.w, cy2) - max((int)rb0.y, cy1); ih = max(ih, 0);
                        int I = iw * ih; int P = ra0 + car;
                        wb0 = __ballot(cv && (I < P) && (3*I > P));
                    }
                    {
                        int iw = min((int)rb1.z, cx2) - max((int)rb1.x, cx1); iw = max(iw, 0);
                        int ih = min((int)rb1.w, cy2) - max((int)rb1.y, cy1); ih = max(ih, 0);
                        int I = iw * ih; int P = ra1 + car;
                        wb1 = __ballot(cv && (I < P) && (3*I > P));
                    }
                    {
                        int iw = min((int)rb2.z, cx2) - max((int)rb2.x, cx1); iw = max(iw, 0);
                        int ih = min((int)rb2.w, cy2) - max((int)rb2.y, cy1); ih = max(ih, 0);
                        int I = iw * ih; int P = ra2 + car;
                        wb2 = __ballot(cv && (I < P) && (3*I > P));
                    }
                    {
                        int iw = min((int)rb3.z, cx2) - max((int)rb3.x, cx1); iw = max(iw, 0);
                        int ih = min((int)rb3.w, cy2) - max((int)rb3.y, cy1); ih = max(ih, 0);
                        int I = iw * ih; int P = ra3 + car;
                        wb3 = __ballot(cv && (I < P) && (3*I > P));
                    }
                    if (lane < 4) {
                        int r = r0 + lane;
                        if (r < n) {
                            u64 word = (lane == 0) ? wb0 : (lane == 1) ? wb1 : (lane == 2) ? wb2 : wb3;
                            int b = r & 63;
                            if (wcol == a) {   // diagonal word: clear cols <= r
                                u64 low = (b == 63) ? ~0ULL : ((1ULL << (b + 1)) - 1);
                                word &= ~low;
                            }
                            buf[rowBase + b * Wa + k] = word;
                        }
                    }
                }
            }
        }
        __syncthreads();

        // ------- Phase E: greedy scan; per-word diag regs, short serial chain -------
        if (tid < 64 && n > 0) {
            int lane = tid;
            u64 fut = 0;
            if (lane < W) {
                int cnt = n - (lane << 6);
                fut = (cnt >= 64) ? ~0ULL : ((1ULL << cnt) - 1);
            }
            int cw = 0;
            u64 cur = (n >= 64) ? ~0ULL : ((1ULL << n) - 1);
            for (;;) {
                int base = 64 * (cw * W - (cw * (cw - 1)) / 2);
                int Wa = W - cw;
                // preload diag word of candidate row (64*cw + lane) into each lane
                u64 rowdiag = 0;
                if ((cur >> lane) & 1ULL) rowdiag = buf[base + lane * Wa];
                // serial in-register greedy within this word
                u64 keptHere = 0;
                while (cur) {
                    int b = (int)__builtin_ctzll(cur);
                    keptHere |= 1ULL << b;
                    u64 w = __shfl(rowdiag, b);
                    cur = (cur & (cur - 1)) & ~w;
                }
                if (lane == 0) keptW[cw] = keptHere;
                // batched future-word suppression for this word's kept rows
                u64 kh = keptHere;
                while (kh) {
                    int b = (int)__builtin_ctzll(kh);
                    kh &= kh - 1;
                    if (lane > cw && lane < W) {
                        u64 rw = buf[base + b * Wa + (lane - cw)];
                        fut &= ~rw;
                    }
                }
                // advance to next non-empty word
                u64 m = __ballot((fut != 0) && (lane > cw));
                if (!m) break;
                int ncw = (int)__builtin_ctzll(m);
                cur = __shfl(fut, ncw);
                cw = ncw;
            }
        }
        __syncthreads();

        // ---------------- Phase F: write kept rows ----------------
        if (tid < n) {
            if ((keptW[tid >> 6] >> (tid & 63)) & 1ULL) {
                u64 key = sKeysG[tid];
                unsigned u = ~(unsigned)(key >> 32);
                float score = __uint_as_float(u ^ 0x80000000u);
                float x1 = (float)mx1i, y1 = (float)my1i;
                out[5*tid+0] = score;
                out[5*tid+1] = x1; out[5*tid+2] = y1;
                out[5*tid+3] = (float)(mx2i - mx1i);
                out[5*tid+4] = (float)(my2i - my1i);
            }
        }
    } else {
        // ============ correctness-only fallback (n > NFAST; never expected) ============
        for (int p = tid; p < n; p += 1024) {
            u64 kp = wsKeys[p];
            int rank = 0;
            for (int q = 0; q < n; ++q) rank += (wsKeys[q] < kp) ? 1 : 0;
            unsigned g = (unsigned)kp;
            unsigned u = ~(unsigned)(kp >> 32);
            float score = __uint_as_float(u ^ 0x80000000u);
            float4 bx = wsBox[g];
            ssc[rank] = score; sx1[rank] = bx.x; sy1[rank] = bx.y;
            sx2[rank] = bx.z;  sy2[rank] = bx.w;
            sar[rank] = (bx.z - bx.x) * (bx.w - bx.y);
        }
        __syncthreads();
        // kept-list arrays overlay wsBox+wsKeys (dead after rank phase): 192 KB >= 160 KB
        float* KX1 = (float*)wsBox;
        float* KY1 = KX1 + 8192;
        float* KX2 = KX1 + 2 * 8192;
        float* KY2 = KX1 + 3 * 8192;
        float* KAR = KX1 + 4 * 8192;
        if (tid < 64) {
            int lane = tid;
            int kc = 0;
            for (int base2 = 0; base2 < n; base2 += 64) {
                int p = base2 + lane;
                bool in = p < n;
                float mx1=0.f,my1=0.f,mx2=0.f,my2=0.f,mar=0.f,msc=0.f;
                if (in) { mx1=sx1[p]; my1=sy1[p]; mx2=sx2[p]; my2=sy2[p]; mar=sar[p]; msc=ssc[p]; }
                bool dead = !in;
                for (int k = 0; k < kc; ++k) {
                    float iw = fminf(mx2, KX2[k]) - fmaxf(mx1, KX1[k]); iw = fmaxf(iw, 0.f);
                    float ih = fminf(my2, KY2[k]) - fmaxf(my1, KY1[k]); ih = fmaxf(ih, 0.f);
                    float inter = iw*ih;
                    float uni = mar + KAR[k] - inter;
                    if (uni > 0.f && inter > 0.5f*uni) dead = true;
                }
                u64 scan = __ballot(!dead);
                while (scan) {
                    int t = (int)__builtin_ctzll(scan);
                    scan &= scan - 1;
                    float tx1=__shfl(mx1,t), ty1=__shfl(my1,t), tx2=__shfl(mx2,t),
                          ty2=__shfl(my2,t), tar=__shfl(mar,t);
                    if (lane == t) {
                        KX1[kc]=mx1; KY1[kc]=my1; KX2[kc]=mx2; KY2[kc]=my2; KAR[kc]=mar;
                        out[5*p+0]=msc; out[5*p+1]=mx1; out[5*p+2]=my1;
                        out[5*p+3]=mx2-mx1; out[5*p+4]=my2-my1;
                    }
                    __threadfence();
                    kc++;
                    bool kill = false;
                    if (!dead && lane > t) {
                        float iw = fminf(mx2,tx2) - fmaxf(mx1,tx1); iw = fmaxf(iw,0.f);
                        float ih = fminf(my2,ty2) - fmaxf(my1,ty1); ih = fmaxf(ih,0.f);
                        float inter = iw*ih;
                        float uni = mar + tar - inter;
                        kill = (uni > 0.f) && (inter > 0.5f*uni);
                    }
                    dead = dead || kill;
                    scan &= ~__ballot(dead);
                }
            }
        }
    }
}

extern "C" void kernel_launch(void* const* d_in, const int* in_sizes, int n_in,
                              void* d_out, int out_size, void* d_ws, size_t ws_size,
                              hipStream_t stream) {
    const float* outs0 = (const float*)d_in[0];
    const float* outs1 = (const float*)d_in[1];
    float* out = (float*)d_out;
    char* ws = (char*)d_ws;
    size_t o = 0;
    float4* wsBox  = (float4*)(ws + o); o += (size_t)8192 * 16;   // 128 KB
    u64*    wsKeys = (u64*)(ws + o);    o += (size_t)8192 * 8;    // 64 KB
    u64*    sKeysG = (u64*)(ws + o);    o += (size_t)1024 * 8;    // 8 KB
    float* ssc = (float*)(ws + o); o += (size_t)8192 * 4;
    float* sx1 = (float*)(ws + o); o += (size_t)8192 * 4;
    float* sy1 = (float*)(ws + o); o += (size_t)8192 * 4;
    float* sx2 = (float*)(ws + o); o += (size_t)8192 * 4;
    float* sy2 = (float*)(ws + o); o += (size_t)8192 * 4;
    float* sar = (float*)(ws + o); o += (size_t)8192 * 4;         // total ~392 KB

    hipLaunchKernelGGL(k_all, dim3(1), dim3(1024), 0, stream,
                       outs0, outs1, out, wsBox, wsKeys, sKeysG,
                       ssc, sx1, sy1, sx2, sy2, sar);
}

// Round 5
// 157.534 us; speedup vs baseline: 1.6561x; 1.1863x over previous
//
#include <hip/hip_runtime.h>
#include <stdint.h>

#pragma clang fp contract(off)

#define NBOX 8000      // 5x40x40 + 5x80x80
#define NFAST 896      // fast path cap: W<=14, tri mask = 6720 u64 = 52.5 KB LDS
#define NB 16          // grid blocks (<< 256 CUs -> co-resident)
#define MAGIC 0x5EEDF1A6u
typedef unsigned long long u64;

// Device-scope grid barrier: one arrival per block on a dedicated slot.
__device__ __forceinline__ void gbar(unsigned* slot) {
    __threadfence();
    __syncthreads();
    if (threadIdx.x == 0) {
        __hip_atomic_fetch_add(slot, 1u, __ATOMIC_ACQ_REL, __HIP_MEMORY_SCOPE_AGENT);
        while (__hip_atomic_load(slot, __ATOMIC_ACQUIRE, __HIP_MEMORY_SCOPE_AGENT) < NB)
            __builtin_amdgcn_s_sleep(1);
    }
    __syncthreads();
}

__global__ __launch_bounds__(1024) void k_all(
    const float* __restrict__ outs0, const float* __restrict__ outs1,
    float* __restrict__ out,
    unsigned* __restrict__ ctrl,       // [0]=flag, [16]=bar0, [32]=bar1, [48]=bar2, [64]=gcnt
    u64* __restrict__ wsKeys,          // [8192] compacted keys
    float4* __restrict__ wsBox,        // [8192] decoded xyxy by original idx g
    u64* __restrict__ sKeysG,          // [1024] sorted keys
    int4* __restrict__ sboxG,          // [1024] sorted int boxes
    u64* __restrict__ triG,            // [6720] triangular suppression mask
    float* __restrict__ ssc, float* __restrict__ sx1, float* __restrict__ sy1,
    float* __restrict__ sx2, float* __restrict__ sy2, float* __restrict__ sar)
{
    __shared__ u64 buf[6720];          // block 0: tri mask copy (52.5 KB)
    __shared__ u64 keptW[16];
    __shared__ int lrank[64];
    __shared__ int sN;
    const int tid = threadIdx.x, bid = blockIdx.x;
    unsigned* flag = ctrl;
    unsigned* b0s = ctrl + 16;
    unsigned* b1s = ctrl + 32;
    unsigned* b2s = ctrl + 48;
    unsigned* gcnt = ctrl + 64;

    // ---- init gate: block 0 zeroes control words (ws is 0xAA-poisoned each launch) ----
    if (bid == 0 && tid == 0) {
        __hip_atomic_store(b0s, 0u, __ATOMIC_RELAXED, __HIP_MEMORY_SCOPE_AGENT);
        __hip_atomic_store(b1s, 0u, __ATOMIC_RELAXED, __HIP_MEMORY_SCOPE_AGENT);
        __hip_atomic_store(b2s, 0u, __ATOMIC_RELAXED, __HIP_MEMORY_SCOPE_AGENT);
        __hip_atomic_store(gcnt, 0u, __ATOMIC_RELAXED, __HIP_MEMORY_SCOPE_AGENT);
        __threadfence();
        __hip_atomic_store(flag, MAGIC, __ATOMIC_RELEASE, __HIP_MEMORY_SCOPE_AGENT);
    }

    // ---- zero d_out (independent of init) ----
    const int gid = bid * 1024 + tid;
    float4* out4 = (float4*)out;               // 40000 f32 = 10000 float4
    if (gid < 10000) out4[gid] = make_float4(0.f, 0.f, 0.f, 0.f);

    if (tid == 0) {
        while (__hip_atomic_load(flag, __ATOMIC_ACQUIRE, __HIP_MEMORY_SCOPE_AGENT) != MAGIC)
            __builtin_amdgcn_s_sleep(1);
    }
    __syncthreads();

    // ---- Phase A: decode + compact (blocks 0..7 active) ----
    if (gid < NBOX) {
        const float* src; int local, i, j; float xps, yps; int pp;
        if (gid < 1600) { src = outs0; local = gid;        i = local/40; j = local - i*40; xps=16.f; yps=12.f; pp=1600; }
        else            { src = outs1; local = gid - 1600; i = local/80; j = local - i*80; xps= 8.f; yps= 6.f; pp=6400; }
        float prob = src[local];
        if (prob > 0.9f) {
            float b1 = src[pp + local], b2 = src[2*pp + local];
            float b3 = src[3*pp + local], b4 = src[4*pp + local];
            // reference: ROW idx i scales x (ii[:,None]); COL idx j scales y
            float c1 = b1*xps + (float)i*xps;
            float c2 = b2*yps + (float)j*yps;
            float X1 = rintf(c1), Y1 = rintf(c2);
            float X2 = rintf(b3*640.0f + c1), Y2 = rintf(b4*480.0f + c2);
            unsigned pos = atomicAdd(gcnt, 1u);          // device-scope by default
            unsigned u = __float_as_uint(prob);
            u ^= (u & 0x80000000u) ? 0xFFFFFFFFu : 0x80000000u;  // monotone map
            u64 key = ((u64)(~u) << 32) | (unsigned)gid; // asc = desc score, asc g
            if (pos < 8192u) wsKeys[pos] = key;
            wsBox[gid] = make_float4(X1, Y1, X2, Y2);
        }
    }

    gbar(b0s);
    if (tid == 0) sN = (int)__hip_atomic_load(gcnt, __ATOMIC_ACQUIRE, __HIP_MEMORY_SCOPE_AGENT);
    __syncthreads();
    int n = sN; if (n > NBOX) n = NBOX;
    const int wv = tid >> 6, lane = tid & 63;

    if (n <= NFAST) {
        const int W = (n + 63) >> 6;

        // ---- Phase B: parallel rank-count sort ----
        // p ≡ bid (mod 16), p = bid + 16*lane; waves split the q-range 16 ways.
        if (tid < 64) lrank[tid] = 0;
        __syncthreads();
        {
            int p = bid + (lane << 4);
            bool pv = p < n;
            u64 kp = pv ? wsKeys[p] : ~0ULL;
            int qchunk = (n + 15) >> 4;
            int qlo = wv * qchunk, qhi = min(qlo + qchunk, n);
            int cnt = 0;
            for (int q = qlo; q < qhi; ++q) {
                u64 kq = wsKeys[q];
                if (pv && kq < kp) cnt++;
            }
            if (cnt) atomicAdd(&lrank[lane], cnt);
        }
        __syncthreads();
        if (tid < 64) {
            int p = bid + (tid << 4);
            if (p < n) {
                u64 key = wsKeys[p];
                int rank = lrank[tid];
                float4 bx = wsBox[(unsigned)key];
                sKeysG[rank] = key;
                sboxG[rank] = make_int4((int)bx.x, (int)bx.y, (int)bx.z, (int)bx.w);
            }
        }
        gbar(b1s);

        // ---- Phase C: tri mask over 256 waves (row-quad per wave) ----
        {
            int nq = (n + 3) >> 2;
            for (int rq = bid * 16 + wv; rq < nq; rq += NB * 16) {
                int r0 = rq << 2;
                int a = r0 >> 6;
                int rowBase = 64 * (a * W - (a * (a - 1)) / 2);
                int Wa = W - a;
                int rr1 = min(r0+1, n-1), rr2 = min(r0+2, n-1), rr3 = min(r0+3, n-1);
                int4 rb0 = sboxG[r0], rb1 = sboxG[rr1], rb2 = sboxG[rr2], rb3 = sboxG[rr3];
                int ra0 = __mul24(rb0.z-rb0.x, rb0.w-rb0.y);
                int ra1 = __mul24(rb1.z-rb1.x, rb1.w-rb1.y);
                int ra2 = __mul24(rb2.z-rb2.x, rb2.w-rb2.y);
                int ra3 = __mul24(rb3.z-rb3.x, rb3.w-rb3.y);
                for (int k = 0; k < Wa; ++k) {
                    int wcol = a + k;
                    int c = (wcol << 6) + lane;
                    bool cv = c < n;
                    int4 cb = sboxG[cv ? c : (n - 1)];
                    int car = __mul24(cb.z-cb.x, cb.w-cb.y);
                    u64 wb0, wb1, wb2, wb3;
                    {
                        int iw = max(min(rb0.z, cb.z) - max(rb0.x, cb.x), 0);
                        int ih = max(min(rb0.w, cb.w) - max(rb0.y, cb.y), 0);
                        int I = __mul24(iw, ih); int P = ra0 + car;
                        wb0 = __ballot(cv && (I < P) && (3*I > P));   // exact ints < 2^23
                    }
                    {
                        int iw = max(min(rb1.z, cb.z) - max(rb1.x, cb.x), 0);
                        int ih = max(min(rb1.w, cb.w) - max(rb1.y, cb.y), 0);
                        int I = __mul24(iw, ih); int P = ra1 + car;
                        wb1 = __ballot(cv && (I < P) && (3*I > P));
                    }
                    {
                        int iw = max(min(rb2.z, cb.z) - max(rb2.x, cb.x), 0);
                        int ih = max(min(rb2.w, cb.w) - max(rb2.y, cb.y), 0);
                        int I = __mul24(iw, ih); int P = ra2 + car;
                        wb2 = __ballot(cv && (I < P) && (3*I > P));
                    }
                    {
                        int iw = max(min(rb3.z, cb.z) - max(rb3.x, cb.x), 0);
                        int ih = max(min(rb3.w, cb.w) - max(rb3.y, cb.y), 0);
                        int I = __mul24(iw, ih); int P = ra3 + car;
                        wb3 = __ballot(cv && (I < P) && (3*I > P));
                    }
                    if (lane < 4) {
                        int r = r0 + lane;
                        if (r < n) {
                            u64 word = (lane == 0) ? wb0 : (lane == 1) ? wb1 : (lane == 2) ? wb2 : wb3;
                            int b = r & 63;
                            if (wcol == a) {   // diagonal word: clear cols <= r
                                u64 low = (b == 63) ? ~0ULL : ((1ULL << (b + 1)) - 1);
                                word &= ~low;
                            }
                            triG[rowBase + b * Wa + k] = word;
                        }
                    }
                }
            }
        }
        gbar(b2s);
        if (bid != 0) return;

        // ---- Phase D (block 0): load tri to LDS, greedy scan, write kept ----
        {
            int A = n >> 6, B = n & 63;
            int total = 64 * (A * W - (A * (A - 1)) / 2) + B * (W - A);
            for (int t = tid; t < total; t += 1024) buf[t] = triG[t];
            if (tid < 16) keptW[tid] = 0;
            __syncthreads();

            if (tid < 64 && n > 0) {
                u64 fut = 0;
                if (lane < W) {
                    int cnt = n - (lane << 6);
                    fut = (cnt >= 64) ? ~0ULL : ((1ULL << cnt) - 1);
                }
                int cw = 0;
                u64 cur = (n >= 64) ? ~0ULL : ((1ULL << n) - 1);
                for (;;) {
                    int base = 64 * (cw * W - (cw * (cw - 1)) / 2);
                    int Wa = W - cw;
                    u64 rowdiag = 0;
                    if ((cur >> lane) & 1ULL) rowdiag = buf[base + lane * Wa];
                    u64 keptHere = 0;
                    while (cur) {
                        int b = (int)__builtin_ctzll(cur);
                        keptHere |= 1ULL << b;
                        u64 w = __shfl(rowdiag, b);
                        cur = (cur & (cur - 1)) & ~w;
                    }
                    if (lane == 0) keptW[cw] = keptHere;
                    u64 kh = keptHere;
                    while (kh) {
                        int b = (int)__builtin_ctzll(kh);
                        kh &= kh - 1;
                        if (lane > cw && lane < W) {
                            u64 rw = buf[base + b * Wa + (lane - cw)];
                            fut &= ~rw;
                        }
                    }
                    u64 m = __ballot((fut != 0) && (lane > cw));
                    if (!m) break;
                    int ncw = (int)__builtin_ctzll(m);
                    cur = __shfl(fut, ncw);
                    cw = ncw;
                }
            }
            __syncthreads();

            if (tid < n && ((keptW[tid >> 6] >> (tid & 63)) & 1ULL)) {
                u64 key = sKeysG[tid];
                unsigned u = ~(unsigned)(key >> 32);
                float score = __uint_as_float(u ^ 0x80000000u);
                int4 bx = sboxG[tid];
                out[5*tid+0] = score;
                out[5*tid+1] = (float)bx.x;
                out[5*tid+2] = (float)bx.y;
                out[5*tid+3] = (float)(bx.z - bx.x);
                out[5*tid+4] = (float)(bx.w - bx.y);
            }
        }
    } else {
        // ============ correctness-only fallback (n > NFAST; never expected) ============
        gbar(b1s);
        gbar(b2s);
        if (bid != 0) return;
        for (int p = tid; p < n; p += 1024) {
            u64 kp = wsKeys[p];
            int rank = 0;
            for (int q = 0; q < n; ++q) rank += (wsKeys[q] < kp) ? 1 : 0;
            unsigned g = (unsigned)kp;
            unsigned u = ~(unsigned)(kp >> 32);
            float score = __uint_as_float(u ^ 0x80000000u);
            float4 bx = wsBox[g];
            ssc[rank] = score; sx1[rank] = bx.x; sy1[rank] = bx.y;
            sx2[rank] = bx.z;  sy2[rank] = bx.w;
            sar[rank] = (bx.z - bx.x) * (bx.w - bx.y);
        }
        __threadfence();
        __syncthreads();
        if (tid < 64) {
            // kept list overlays wsBox/wsKeys (dead after rank)
            float* KX1 = (float*)wsBox;
            float* KY1 = KX1 + 8192;
            float* KX2 = KX1 + 2 * 8192;
            float* KY2 = KX1 + 3 * 8192;
            float* KAR = KX1 + 4 * 8192;
            int kc = 0;
            for (int base2 = 0; base2 < n; base2 += 64) {
                int p = base2 + lane;
                bool in = p < n;
                float mx1=0.f,my1=0.f,mx2=0.f,my2=0.f,mar=0.f,msc=0.f;
                if (in) { mx1=sx1[p]; my1=sy1[p]; mx2=sx2[p]; my2=sy2[p]; mar=sar[p]; msc=ssc[p]; }
                bool dead = !in;
                for (int k = 0; k < kc; ++k) {
                    float iw = fminf(mx2, KX2[k]) - fmaxf(mx1, KX1[k]); iw = fmaxf(iw, 0.f);
                    float ih = fminf(my2, KY2[k]) - fmaxf(my1, KY1[k]); ih = fmaxf(ih, 0.f);
                    float inter = iw*ih;
                    float uni = mar + KAR[k] - inter;
                    if (uni > 0.f && inter > 0.5f*uni) dead = true;
                }
                u64 scan = __ballot(!dead);
                while (scan) {
                    int t = (int)__builtin_ctzll(scan);
                    scan &= scan - 1;
                    float tx1=__shfl(mx1,t), ty1=__shfl(my1,t), tx2=__shfl(mx2,t),
                          ty2=__shfl(my2,t), tar=__shfl(mar,t);
                    if (lane == t) {
                        KX1[kc]=mx1; KY1[kc]=my1; KX2[kc]=mx2; KY2[kc]=my2; KAR[kc]=mar;
                        out[5*p+0]=msc; out[5*p+1]=mx1; out[5*p+2]=my1;
                        out[5*p+3]=mx2-mx1; out[5*p+4]=my2-my1;
                    }
                    __threadfence();
                    kc++;
                    bool kill = false;
                    if (!dead && lane > t) {
                        float iw = fminf(mx2,tx2) - fmaxf(mx1,tx1); iw = fmaxf(iw,0.f);
                        float ih = fminf(my2,ty2) - fmaxf(my1,ty1); ih = fmaxf(ih,0.f);
                        float inter = iw*ih;
                        float uni = mar + tar - inter;
                        kill = (uni > 0.f) && (inter > 0.5f*uni);
                    }
                    dead = dead || kill;
                    scan &= ~__ballot(dead);
                }
            }
        }
    }
}

extern "C" void kernel_launch(void* const* d_in, const int* in_sizes, int n_in,
                              void* d_out, int out_size, void* d_ws, size_t ws_size,
                              hipStream_t stream) {
    const float* outs0 = (const float*)d_in[0];
    const float* outs1 = (const float*)d_in[1];
    float* out = (float*)d_out;
    char* ws = (char*)d_ws;
    size_t o = 0;
    unsigned* ctrl  = (unsigned*)(ws + o); o += 512;
    u64* wsKeys     = (u64*)(ws + o);      o += (size_t)8192 * 8;    // 64 KB
    float4* wsBox   = (float4*)(ws + o);   o += (size_t)8192 * 16;   // 128 KB
    u64* sKeysG     = (u64*)(ws + o);      o += (size_t)1024 * 8;    // 8 KB
    int4* sboxG     = (int4*)(ws + o);     o += (size_t)1024 * 16;   // 16 KB
    u64* triG       = (u64*)(ws + o);      o += (size_t)6720 * 8;    // 52.5 KB
    float* ssc = (float*)(ws + o); o += (size_t)8192 * 4;
    float* sx1 = (float*)(ws + o); o += (size_t)8192 * 4;
    float* sy1 = (float*)(ws + o); o += (size_t)8192 * 4;
    float* sx2 = (float*)(ws + o); o += (size_t)8192 * 4;
    float* sy2 = (float*)(ws + o); o += (size_t)8192 * 4;
    float* sar = (float*)(ws + o); o += (size_t)8192 * 4;            // total ~461 KB

    hipLaunchKernelGGL(k_all, dim3(NB), dim3(1024), 0, stream,
                       outs0, outs1, out, ctrl, wsKeys, wsBox,
                       sKeysG, sboxG, triG, ssc, sx1, sy1, sx2, sy2, sar);
}

// Round 6
// 144.705 us; speedup vs baseline: 1.8030x; 1.0887x over previous
//
#include <hip/hip_runtime.h>
#include <stdint.h>

#pragma clang fp contract(off)

#define NBOX 8000      // 5x40x40 + 5x80x80
#define NFAST 896      // fast path cap: W<=14, tri mask = 6720 u64 = 52.5 KB LDS
#define NB 16          // grid blocks (<< 256 CUs -> co-resident)
#define MAGIC 0x5EEDF1A6u
typedef unsigned long long u64;

// Slim device-scope grid barrier: relaxed polls + one acquire fence on exit.
__device__ __forceinline__ void gbar(unsigned* slot) {
    __syncthreads();   // per-wave s_waitcnt vmcnt(0) before s_barrier drains stores to L2
    if (threadIdx.x == 0) {
        __hip_atomic_fetch_add(slot, 1u, __ATOMIC_ACQ_REL, __HIP_MEMORY_SCOPE_AGENT);
        while (__hip_atomic_load(slot, __ATOMIC_RELAXED, __HIP_MEMORY_SCOPE_AGENT) < NB)
            __builtin_amdgcn_s_sleep(2);
        __builtin_amdgcn_fence(__ATOMIC_ACQUIRE, "agent");
    }
    __syncthreads();
}

__global__ __launch_bounds__(1024) void k_all(
    const float* __restrict__ outs0, const float* __restrict__ outs1,
    float* __restrict__ out,
    unsigned* __restrict__ ctrl,       // [0]=flag, [16]=bar0, [32]=bar1, [48]=bar2, [64]=gcnt
    u64* __restrict__ wsKeys,          // [8192] compacted keys
    float4* __restrict__ wsBox,        // [8192] decoded xyxy by original idx g
    u64* __restrict__ sKeysG,          // [1024] sorted keys
    int4* __restrict__ sboxG,          // [1024] sorted int boxes
    u64* __restrict__ triG,            // [6720] triangular suppression mask
    float* __restrict__ ssc, float* __restrict__ sx1, float* __restrict__ sy1,
    float* __restrict__ sx2, float* __restrict__ sy2, float* __restrict__ sar)
{
    __shared__ u64 buf[6720];          // block 0: tri mask copy (52.5 KB)
    __shared__ u64 keptW[16];
    __shared__ int lrank[64];
    __shared__ int sN;
    const int tid = threadIdx.x, bid = blockIdx.x;
    unsigned* flag = ctrl;
    unsigned* b0s = ctrl + 16;
    unsigned* b1s = ctrl + 32;
    unsigned* b2s = ctrl + 48;
    unsigned* gcnt = ctrl + 64;

    // ---- init gate: block 0 zeroes control words (ws is 0xAA-poisoned each launch) ----
    if (bid == 0 && tid == 0) {
        __hip_atomic_store(b0s, 0u, __ATOMIC_RELAXED, __HIP_MEMORY_SCOPE_AGENT);
        __hip_atomic_store(b1s, 0u, __ATOMIC_RELAXED, __HIP_MEMORY_SCOPE_AGENT);
        __hip_atomic_store(b2s, 0u, __ATOMIC_RELAXED, __HIP_MEMORY_SCOPE_AGENT);
        __hip_atomic_store(gcnt, 0u, __ATOMIC_RELAXED, __HIP_MEMORY_SCOPE_AGENT);
        __hip_atomic_store(flag, MAGIC, __ATOMIC_RELEASE, __HIP_MEMORY_SCOPE_AGENT);
    }

    // ---- zero d_out (independent of init) ----
    const int gid = bid * 1024 + tid;
    float4* out4 = (float4*)out;               // 40000 f32 = 10000 float4
    if (gid < 10000) out4[gid] = make_float4(0.f, 0.f, 0.f, 0.f);

    if (tid == 0) {
        while (__hip_atomic_load(flag, __ATOMIC_RELAXED, __HIP_MEMORY_SCOPE_AGENT) != MAGIC)
            __builtin_amdgcn_s_sleep(2);
        __builtin_amdgcn_fence(__ATOMIC_ACQUIRE, "agent");
    }
    __syncthreads();

    // ---- Phase A: decode + compact ----
    if (gid < NBOX) {
        const float* src; int local, i, j; float xps, yps; int pp;
        if (gid < 1600) { src = outs0; local = gid;        i = local/40; j = local - i*40; xps=16.f; yps=12.f; pp=1600; }
        else            { src = outs1; local = gid - 1600; i = local/80; j = local - i*80; xps= 8.f; yps= 6.f; pp=6400; }
        float prob = src[local];
        if (prob > 0.9f) {
            float b1 = src[pp + local], b2 = src[2*pp + local];
            float b3 = src[3*pp + local], b4 = src[4*pp + local];
            // reference: ROW idx i scales x (ii[:,None]); COL idx j scales y
            float c1 = b1*xps + (float)i*xps;
            float c2 = b2*yps + (float)j*yps;
            float X1 = rintf(c1), Y1 = rintf(c2);
            float X2 = rintf(b3*640.0f + c1), Y2 = rintf(b4*480.0f + c2);
            unsigned pos = atomicAdd(gcnt, 1u);          // device-scope
            unsigned u = __float_as_uint(prob);
            u ^= (u & 0x80000000u) ? 0xFFFFFFFFu : 0x80000000u;  // monotone map
            u64 key = ((u64)(~u) << 32) | (unsigned)gid; // asc = desc score, asc g
            if (pos < 8192u) wsKeys[pos] = key;
            wsBox[gid] = make_float4(X1, Y1, X2, Y2);
        }
    }

    gbar(b0s);
    if (tid == 0) sN = (int)__hip_atomic_load(gcnt, __ATOMIC_RELAXED, __HIP_MEMORY_SCOPE_AGENT);
    __syncthreads();
    int n = sN; if (n > NBOX) n = NBOX;
    const int wv = tid >> 6, lane = tid & 63;

    if (n <= NFAST) {
        const int W = (n + 63) >> 6;

        // ---- Phase B: parallel rank-count sort ----
        // p ≡ bid (mod 16), p = bid + 16*lane; waves split the q-range 16 ways.
        if (tid < 64) lrank[tid] = 0;
        __syncthreads();
        {
            int p = bid + (lane << 4);
            bool pv = p < n;
            u64 kp = pv ? wsKeys[p] : ~0ULL;
            int qchunk = (n + 15) >> 4;
            int qlo = wv * qchunk, qhi = min(qlo + qchunk, n);
            int cnt = 0;
            for (int q = qlo; q < qhi; ++q) {
                u64 kq = wsKeys[q];
                if (pv && kq < kp) cnt++;
            }
            if (cnt) atomicAdd(&lrank[lane], cnt);
        }
        __syncthreads();
        if (tid < 64) {
            int p = bid + (tid << 4);
            if (p < n) {
                u64 key = wsKeys[p];
                int rank = lrank[tid];
                float4 bx = wsBox[(unsigned)key];
                sKeysG[rank] = key;
                sboxG[rank] = make_int4((int)bx.x, (int)bx.y, (int)bx.z, (int)bx.w);
            }
        }
        gbar(b1s);

        // ---- Phase C: tri mask over 256 waves (row-quad per wave) ----
        {
            int nq = (n + 3) >> 2;
            for (int rq = bid * 16 + wv; rq < nq; rq += NB * 16) {
                int r0 = rq << 2;
                int a = r0 >> 6;
                int rowBase = 64 * (a * W - (a * (a - 1)) / 2);
                int Wa = W - a;
                int rr1 = min(r0+1, n-1), rr2 = min(r0+2, n-1), rr3 = min(r0+3, n-1);
                int4 rb0 = sboxG[r0], rb1 = sboxG[rr1], rb2 = sboxG[rr2], rb3 = sboxG[rr3];
                int ra0 = __mul24(rb0.z-rb0.x, rb0.w-rb0.y);
                int ra1 = __mul24(rb1.z-rb1.x, rb1.w-rb1.y);
                int ra2 = __mul24(rb2.z-rb2.x, rb2.w-rb2.y);
                int ra3 = __mul24(rb3.z-rb3.x, rb3.w-rb3.y);
                for (int k = 0; k < Wa; ++k) {
                    int wcol = a + k;
                    int c = (wcol << 6) + lane;
                    bool cv = c < n;
                    int4 cb = sboxG[cv ? c : (n - 1)];
                    int car = __mul24(cb.z-cb.x, cb.w-cb.y);
                    u64 wb0, wb1, wb2, wb3;
                    {
                        int iw = max(min(rb0.z, cb.z) - max(rb0.x, cb.x), 0);
                        int ih = max(min(rb0.w, cb.w) - max(rb0.y, cb.y), 0);
                        int I = __mul24(iw, ih); int P = ra0 + car;
                        wb0 = __ballot(cv && (I < P) && (3*I > P));   // exact ints < 2^23
                    }
                    {
                        int iw = max(min(rb1.z, cb.z) - max(rb1.x, cb.x), 0);
                        int ih = max(min(rb1.w, cb.w) - max(rb1.y, cb.y), 0);
                        int I = __mul24(iw, ih); int P = ra1 + car;
                        wb1 = __ballot(cv && (I < P) && (3*I > P));
                    }
                    {
                        int iw = max(min(rb2.z, cb.z) - max(rb2.x, cb.x), 0);
                        int ih = max(min(rb2.w, cb.w) - max(rb2.y, cb.y), 0);
                        int I = __mul24(iw, ih); int P = ra2 + car;
                        wb2 = __ballot(cv && (I < P) && (3*I > P));
                    }
                    {
                        int iw = max(min(rb3.z, cb.z) - max(rb3.x, cb.x), 0);
                        int ih = max(min(rb3.w, cb.w) - max(rb3.y, cb.y), 0);
                        int I = __mul24(iw, ih); int P = ra3 + car;
                        wb3 = __ballot(cv && (I < P) && (3*I > P));
                    }
                    if (lane < 4) {
                        int r = r0 + lane;
                        if (r < n) {
                            u64 word = (lane == 0) ? wb0 : (lane == 1) ? wb1 : (lane == 2) ? wb2 : wb3;
                            int b = r & 63;
                            if (wcol == a) {   // diagonal word: clear cols <= r
                                u64 low = (b == 63) ? ~0ULL : ((1ULL << (b + 1)) - 1);
                                word &= ~low;
                            }
                            triG[rowBase + b * Wa + k] = word;
                        }
                    }
                }
            }
        }
        gbar(b2s);
        if (bid != 0) return;

        // ---- Phase D (block 0): tri -> LDS, SCALAR-PIPE greedy scan, write kept ----
        {
            int A = n >> 6, B = n & 63;
            int total = 64 * (A * W - (A * (A - 1)) / 2) + B * (W - A);
            for (int t = tid; t < total; t += 1024) buf[t] = triG[t];
            if (tid < 16) keptW[tid] = 0;
            __syncthreads();

            if (tid < 64 && n > 0) {
                u64 fut = 0;
                if (lane < W) {
                    int cnt = n - (lane << 6);
                    fut = (cnt >= 64) ? ~0ULL : ((1ULL << cnt) - 1);
                }
                // cur as wave-uniform u32 halves (SGPR-resident)
                unsigned curLo, curHi;
                {
                    u64 c0 = (n >= 64) ? ~0ULL : ((1ULL << n) - 1);
                    curLo = (unsigned)__builtin_amdgcn_readfirstlane((int)(unsigned)c0);
                    curHi = (unsigned)__builtin_amdgcn_readfirstlane((int)(unsigned)(c0 >> 32));
                }
                int cw = 0;
                for (;;) {
                    int base = 64 * (cw * W - (cw * (cw - 1)) / 2);
                    int Wa = W - cw;
                    // preload diag word of row (64*cw + lane) into this lane's regs
                    unsigned rdLo = 0, rdHi = 0;
                    {
                        int r = (cw << 6) + lane;
                        if (r < n) {
                            u64 v = buf[base + lane * Wa];
                            rdLo = (unsigned)v; rdHi = (unsigned)(v >> 32);
                        }
                    }
                    // serial in-word greedy: scalar ctz + v_readlane, no ds_bpermute
                    unsigned khLo = 0, khHi = 0;
                    while (curLo | curHi) {
                        int b = curLo ? __builtin_ctz(curLo) : (32 + __builtin_ctz(curHi));
                        unsigned wLo = (unsigned)__builtin_amdgcn_readlane((int)rdLo, b);
                        unsigned wHi = (unsigned)__builtin_amdgcn_readlane((int)rdHi, b);
                        if (curLo) { khLo |= curLo & (0u - curLo); curLo &= curLo - 1; }
                        else       { khHi |= curHi & (0u - curHi); curHi &= curHi - 1; }
                        curLo &= ~wLo; curHi &= ~wHi;
                    }
                    if (lane == 0) keptW[cw] = ((u64)khHi << 32) | khLo;
                    // batched future-word suppression for this word's kept rows
                    {
                        bool act = (lane > cw) && (lane < W);
                        int off0 = base + (lane - cw);
                        unsigned kl = khLo, kh = khHi;
                        while (kl | kh) {
                            int b = kl ? __builtin_ctz(kl) : (32 + __builtin_ctz(kh));
                            if (kl) kl &= kl - 1; else kh &= kh - 1;
                            if (act) fut &= ~buf[off0 + b * Wa];
                        }
                    }
                    // advance to next non-empty word
                    u64 m = __ballot((fut != 0) && (lane > cw));
                    if (!m) break;
                    int ncw = (int)__builtin_ctzll(m);
                    curLo = (unsigned)__builtin_amdgcn_readlane((int)(unsigned)fut, ncw);
                    curHi = (unsigned)__builtin_amdgcn_readlane((int)(unsigned)(fut >> 32), ncw);
                    cw = ncw;
                }
            }
            __syncthreads();

            if (tid < n && ((keptW[tid >> 6] >> (tid & 63)) & 1ULL)) {
                u64 key = sKeysG[tid];
                unsigned u = ~(unsigned)(key >> 32);
                float score = __uint_as_float(u ^ 0x80000000u);
                int4 bx = sboxG[tid];
                out[5*tid+0] = score;
                out[5*tid+1] = (float)bx.x;
                out[5*tid+2] = (float)bx.y;
                out[5*tid+3] = (float)(bx.z - bx.x);
                out[5*tid+4] = (float)(bx.w - bx.y);
            }
        }
    } else {
        // ============ correctness-only fallback (n > NFAST; never expected) ============
        gbar(b1s);
        gbar(b2s);
        if (bid != 0) return;
        for (int p = tid; p < n; p += 1024) {
            u64 kp = wsKeys[p];
            int rank = 0;
            for (int q = 0; q < n; ++q) rank += (wsKeys[q] < kp) ? 1 : 0;
            unsigned g = (unsigned)kp;
            unsigned u = ~(unsigned)(kp >> 32);
            float score = __uint_as_float(u ^ 0x80000000u);
            float4 bx = wsBox[g];
            ssc[rank] = score; sx1[rank] = bx.x; sy1[rank] = bx.y;
            sx2[rank] = bx.z;  sy2[rank] = bx.w;
            sar[rank] = (bx.z - bx.x) * (bx.w - bx.y);
        }
        __threadfence();
        __syncthreads();
        if (tid < 64) {
            // kept list overlays wsBox/wsKeys (dead after rank)
            float* KX1 = (float*)wsBox;
            float* KY1 = KX1 + 8192;
            float* KX2 = KX1 + 2 * 8192;
            float* KY2 = KX1 + 3 * 8192;
            float* KAR = KX1 + 4 * 8192;
            int kc = 0;
            for (int base2 = 0; base2 < n; base2 += 64) {
                int p = base2 + lane;
                bool in = p < n;
                float mx1=0.f,my1=0.f,mx2=0.f,my2=0.f,mar=0.f,msc=0.f;
                if (in) { mx1=sx1[p]; my1=sy1[p]; mx2=sx2[p]; my2=sy2[p]; mar=sar[p]; msc=ssc[p]; }
                bool dead = !in;
                for (int k = 0; k < kc; ++k) {
                    float iw = fminf(mx2, KX2[k]) - fmaxf(mx1, KX1[k]); iw = fmaxf(iw, 0.f);
                    float ih = fminf(my2, KY2[k]) - fmaxf(my1, KY1[k]); ih = fmaxf(ih, 0.f);
                    float inter = iw*ih;
                    float uni = mar + KAR[k] - inter;
                    if (uni > 0.f && inter > 0.5f*uni) dead = true;
                }
                u64 scan = __ballot(!dead);
                while (scan) {
                    int t = (int)__builtin_ctzll(scan);
                    scan &= scan - 1;
                    float tx1=__shfl(mx1,t), ty1=__shfl(my1,t), tx2=__shfl(mx2,t),
                          ty2=__shfl(my2,t), tar=__shfl(mar,t);
                    if (lane == t) {
                        KX1[kc]=mx1; KY1[kc]=my1; KX2[kc]=mx2; KY2[kc]=my2; KAR[kc]=mar;
                        out[5*p+0]=msc; out[5*p+1]=mx1; out[5*p+2]=my1;
                        out[5*p+3]=mx2-mx1; out[5*p+4]=my2-my1;
                    }
                    __threadfence();
                    kc++;
                    bool kill = false;
                    if (!dead && lane > t) {
                        float iw = fminf(mx2,tx2) - fmaxf(mx1,tx1); iw = fmaxf(iw,0.f);
                        float ih = fminf(my2,ty2) - fmaxf(my1,ty1); ih = fmaxf(ih,0.f);
                        float inter = iw*ih;
                        float uni = mar + tar - inter;
                        kill = (uni > 0.f) && (inter > 0.5f*uni);
                    }
                    dead = dead || kill;
                    scan &= ~__ballot(dead);
                }
            }
        }
    }
}

extern "C" void kernel_launch(void* const* d_in, const int* in_sizes, int n_in,
                              void* d_out, int out_size, void* d_ws, size_t ws_size,
                              hipStream_t stream) {
    const float* outs0 = (const float*)d_in[0];
    const float* outs1 = (const float*)d_in[1];
    float* out = (float*)d_out;
    char* ws = (char*)d_ws;
    size_t o = 0;
    unsigned* ctrl  = (unsigned*)(ws + o); o += 512;
    u64* wsKeys     = (u64*)(ws + o);      o += (size_t)8192 * 8;    // 64 KB
    float4* wsBox   = (float4*)(ws + o);   o += (size_t)8192 * 16;   // 128 KB
    u64* sKeysG     = (u64*)(ws + o);      o += (size_t)1024 * 8;    // 8 KB
    int4* sboxG     = (int4*)(ws + o);     o += (size_t)1024 * 16;   // 16 KB
    u64* triG       = (u64*)(ws + o);      o += (size_t)6720 * 8;    // 52.5 KB
    float* ssc = (float*)(ws + o); o += (size_t)8192 * 4;
    float* sx1 = (float*)(ws + o); o += (size_t)8192 * 4;
    float* sy1 = (float*)(ws + o); o += (size_t)8192 * 4;
    float* sx2 = (float*)(ws + o); o += (size_t)8192 * 4;
    float* sy2 = (float*)(ws + o); o += (size_t)8192 * 4;
    float* sar = (float*)(ws + o); o += (size_t)8192 * 4;            // total ~461 KB

    hipLaunchKernelGGL(k_all, dim3(NB), dim3(1024), 0, stream,
                       outs0, outs1, out, ctrl, wsKeys, wsBox,
                       sKeysG, sboxG, triG, ssc, sx1, sy1, sx2, sy2, sar);
}

// Round 7
// 142.178 us; speedup vs baseline: 1.8350x; 1.0178x over previous
//
#include <hip/hip_runtime.h>
#include <stdint.h>

#pragma clang fp contract(off)

#define NBOX 8000      // 5x40x40 + 5x80x80
#define NFAST 896      // fast path cap: W<=14, tri mask = 6720 u64 = 52.5 KB LDS
#define WMAX 14
#define NB 16          // grid blocks (<< 256 CUs -> co-resident)
#define MAGIC 0x5EEDF1A6u
typedef unsigned long long u64;

// Agent-coherent (sc1) relaxed atomics: bypass the non-coherent per-XCD L2,
// land in / read from the shared MALL. No buffer_wbl2 / buffer_inv emitted.
__device__ __forceinline__ u64 aload(u64* p) {
    return __hip_atomic_load(p, __ATOMIC_RELAXED, __HIP_MEMORY_SCOPE_AGENT);
}
__device__ __forceinline__ void astore(u64* p, u64 v) {
    __hip_atomic_store(p, v, __ATOMIC_RELAXED, __HIP_MEMORY_SCOPE_AGENT);
}

// Fence-free grid barrier: all cross-block data moves via sc1 accesses;
// __syncthreads drains vmcnt(0) before arrival, so the relaxed counter
// increment is ordered after the data reaches the device coherence point.
__device__ __forceinline__ void gbar(unsigned* slot) {
    __syncthreads();
    if (threadIdx.x == 0) {
        __hip_atomic_fetch_add(slot, 1u, __ATOMIC_RELAXED, __HIP_MEMORY_SCOPE_AGENT);
        while (__hip_atomic_load(slot, __ATOMIC_RELAXED, __HIP_MEMORY_SCOPE_AGENT) < NB)
            __builtin_amdgcn_s_sleep(1);
    }
    __syncthreads();
}

// pack 4 non-negative u16 coords into one u64: x1 | y1<<16 | x2<<32 | y2<<48
__device__ __forceinline__ u64 packBox(int x1, int y1, int x2, int y2) {
    return (u64)(unsigned)(x1 | (y1 << 16)) | ((u64)(unsigned)(x2 | (y2 << 16)) << 32);
}
__device__ __forceinline__ void unpackBox(u64 v, int& x1, int& y1, int& x2, int& y2) {
    unsigned lo = (unsigned)v, hi = (unsigned)(v >> 32);
    x1 = (int)(lo & 0xffffu); y1 = (int)(lo >> 16);
    x2 = (int)(hi & 0xffffu); y2 = (int)(hi >> 16);
}
__device__ __forceinline__ u64 iouBit(u64 rp, int ra, int cx1, int cy1, int cx2, int cy2,
                                      int car, bool cv) {
    int rx1, ry1, rx2, ry2; unpackBox(rp, rx1, ry1, rx2, ry2);
    int iw = max(min(rx2, cx2) - max(rx1, cx1), 0);
    int ih = max(min(ry2, cy2) - max(ry1, cy1), 0);
    int I = __mul24(iw, ih); int P = ra + car;          // exact: ints < 2^23
    return __ballot(cv && (I < P) && (3 * I > P));      // uni>0 && inter>0.5*uni
}

__global__ __launch_bounds__(1024) void k_all(
    const float* __restrict__ outs0, const float* __restrict__ outs1,
    float* __restrict__ out,
    unsigned* __restrict__ ctrl,   // [0]=flag,[16]=bar0,[32]=bar1,[48]=bar2,[64]=gcnt
    u64* __restrict__ wsKeysPk,    // [8192] compacted keys
    u64* __restrict__ wsBoxPk,     // [8192] packed boxes by original idx g
    u64* __restrict__ sKeysG,      // [1024] sorted keys
    u64* __restrict__ sBoxPk,      // [1024] sorted packed boxes
    u64* __restrict__ triG,        // [6720] triangular suppression mask
    u64* __restrict__ fbKey, u64* __restrict__ fbBox, u64* __restrict__ kArr)
{
    __shared__ u64 buf[6720];      // block 0: tri mask copy (52.5 KB)
    __shared__ u64 keptW[16];
    __shared__ int lrank[64];
    __shared__ int sN;
    const int tid = threadIdx.x, bid = blockIdx.x;
    unsigned* flag = ctrl;
    unsigned* b0s = ctrl + 16;
    unsigned* b1s = ctrl + 32;
    unsigned* b2s = ctrl + 48;
    unsigned* gcnt = ctrl + 64;

    // ---- init gate: block 0 zeroes control words (ws is 0xAA-poisoned) ----
    if (bid == 0 && tid == 0) {
        __hip_atomic_store(b0s, 0u, __ATOMIC_RELAXED, __HIP_MEMORY_SCOPE_AGENT);
        __hip_atomic_store(b1s, 0u, __ATOMIC_RELAXED, __HIP_MEMORY_SCOPE_AGENT);
        __hip_atomic_store(b2s, 0u, __ATOMIC_RELAXED, __HIP_MEMORY_SCOPE_AGENT);
        __hip_atomic_store(gcnt, 0u, __ATOMIC_RELAXED, __HIP_MEMORY_SCOPE_AGENT);
        __threadfence_block();   // vmcnt(0): slots at MALL before flag (no cache ops)
        __hip_atomic_store(flag, MAGIC, __ATOMIC_RELAXED, __HIP_MEMORY_SCOPE_AGENT);
    }

    // ---- zero d_out ----
    const int gid = bid * 1024 + tid;
    float4* out4 = (float4*)out;               // 40000 f32 = 10000 float4
    if (gid < 10000) out4[gid] = make_float4(0.f, 0.f, 0.f, 0.f);

    // ---- decode into registers BEFORE the gate (overlap flag propagation) ----
    bool valid = false; u64 myKey = 0, myBox = 0;
    if (gid < NBOX) {
        const float* src; int local, i, j; float xps, yps; int pp;
        if (gid < 1600) { src = outs0; local = gid;        i = local/40; j = local - i*40; xps=16.f; yps=12.f; pp=1600; }
        else            { src = outs1; local = gid - 1600; i = local/80; j = local - i*80; xps= 8.f; yps= 6.f; pp=6400; }
        float prob = src[local];
        if (prob > 0.9f) {
            float b1 = src[pp + local], b2 = src[2*pp + local];
            float b3 = src[3*pp + local], b4 = src[4*pp + local];
            // reference: ROW idx i scales x (ii[:,None]); COL idx j scales y
            float c1 = b1*xps + (float)i*xps;
            float c2 = b2*yps + (float)j*yps;
            float X1 = rintf(c1), Y1 = rintf(c2);
            float X2 = rintf(b3*640.0f + c1), Y2 = rintf(b4*480.0f + c2);
            unsigned u = __float_as_uint(prob);
            u ^= (u & 0x80000000u) ? 0xFFFFFFFFu : 0x80000000u;  // monotone map
            myKey = ((u64)(~u) << 32) | (unsigned)gid;  // asc = desc score, asc g
            myBox = packBox((int)X1, (int)Y1, (int)X2, (int)Y2);
            valid = true;
        }
    }

    // ---- gate ----
    if (tid == 0) {
        while (__hip_atomic_load(flag, __ATOMIC_RELAXED, __HIP_MEMORY_SCOPE_AGENT) != MAGIC)
            __builtin_amdgcn_s_sleep(1);
    }
    __syncthreads();

    // ---- publish decoded boxes ----
    if (valid) {
        unsigned pos = __hip_atomic_fetch_add(gcnt, 1u, __ATOMIC_RELAXED, __HIP_MEMORY_SCOPE_AGENT);
        if (pos < 8192u) astore(&wsKeysPk[pos], myKey);
        astore(&wsBoxPk[gid], myBox);
    }

    gbar(b0s);
    if (tid == 0) sN = (int)__hip_atomic_load(gcnt, __ATOMIC_RELAXED, __HIP_MEMORY_SCOPE_AGENT);
    __syncthreads();
    int n = sN; if (n > NBOX) n = NBOX;
    const int wv = tid >> 6, lane = tid & 63;

    if (n <= NFAST) {
        const int W = (n + 63) >> 6;

        // ---- Phase B: parallel rank-count sort (p = bid + 16*lane) ----
        if (tid < 64) lrank[tid] = 0;
        __syncthreads();
        {
            int p = bid + (lane << 4);
            bool pv = p < n;
            u64 kp = pv ? aload(&wsKeysPk[p]) : ~0ULL;
            int qchunk = (n + 15) >> 4;
            int qlo = wv * qchunk, qhi = min(qlo + qchunk, n);
            int cnt = 0;
            for (int q = qlo; q < qhi; ++q) {
                u64 kq = aload(&wsKeysPk[q]);
                if (pv && kq < kp) cnt++;
            }
            if (cnt) atomicAdd(&lrank[lane], cnt);
        }
        __syncthreads();
        if (tid < 64) {
            int p = bid + (tid << 4);
            if (p < n) {
                u64 key = aload(&wsKeysPk[p]);
                int rank = lrank[tid];
                u64 box = aload(&wsBoxPk[(unsigned)key]);
                astore(&sKeysG[rank], key);
                astore(&sBoxPk[rank], box);
            }
        }
        gbar(b1s);

        // ---- Phase C: tri mask over 256 waves; all col loads pre-issued ----
        if (n > 0) {
            int nq = (n + 3) >> 2;
            for (int rq = bid * 16 + wv; rq < nq; rq += NB * 16) {
                int r0 = rq << 2;
                int a = r0 >> 6;
                int rowBase = 64 * (a * W - (a * (a - 1)) / 2);
                int Wa = W - a;
                int rr1 = min(r0+1, n-1), rr2 = min(r0+2, n-1), rr3 = min(r0+3, n-1);
                u64 rp0 = aload(&sBoxPk[r0]), rp1 = aload(&sBoxPk[rr1]);
                u64 rp2 = aload(&sBoxPk[rr2]), rp3 = aload(&sBoxPk[rr3]);
                u64 cbPk[WMAX];
                #pragma unroll
                for (int k = 0; k < WMAX; ++k) {
                    int c = ((a + k) << 6) + lane;
                    int cc = (k < Wa && c < n) ? c : (n - 1);
                    cbPk[k] = aload(&sBoxPk[cc]);
                }
                int t01, t02, t03, t04; unpackBox(rp0, t01, t02, t03, t04);
                int ra0 = __mul24(t03 - t01, t04 - t02);
                unpackBox(rp1, t01, t02, t03, t04);
                int ra1 = __mul24(t03 - t01, t04 - t02);
                unpackBox(rp2, t01, t02, t03, t04);
                int ra2 = __mul24(t03 - t01, t04 - t02);
                unpackBox(rp3, t01, t02, t03, t04);
                int ra3 = __mul24(t03 - t01, t04 - t02);
                #pragma unroll
                for (int k = 0; k < WMAX; ++k) {
                    if (k < Wa) {
                        int wcol = a + k;
                        int c = (wcol << 6) + lane;
                        bool cv = c < n;
                        int cx1, cy1, cx2, cy2; unpackBox(cbPk[k], cx1, cy1, cx2, cy2);
                        int car = __mul24(cx2 - cx1, cy2 - cy1);
                        u64 wb0 = iouBit(rp0, ra0, cx1, cy1, cx2, cy2, car, cv);
                        u64 wb1 = iouBit(rp1, ra1, cx1, cy1, cx2, cy2, car, cv);
                        u64 wb2 = iouBit(rp2, ra2, cx1, cy1, cx2, cy2, car, cv);
                        u64 wb3 = iouBit(rp3, ra3, cx1, cy1, cx2, cy2, car, cv);
                        if (lane < 4) {
                            int r = r0 + lane;
                            if (r < n) {
                                u64 word = (lane == 0) ? wb0 : (lane == 1) ? wb1
                                         : (lane == 2) ? wb2 : wb3;
                                int b = r & 63;
                                if (wcol == a) {   // diagonal word: clear cols <= r
                                    u64 low = (b == 63) ? ~0ULL : ((1ULL << (b + 1)) - 1);
                                    word &= ~low;
                                }
                                astore(&triG[rowBase + b * Wa + k], word);
                            }
                        }
                    }
                }
            }
        }
        gbar(b2s);
        if (bid != 0) return;

        // ---- Phase D (block 0): tri -> LDS, scalar-pipe greedy scan, write ----
        {
            int A = n >> 6, B = n & 63;
            int total = 64 * (A * W - (A * (A - 1)) / 2) + B * (W - A);
            for (int t = tid; t < total; t += 1024) buf[t] = aload(&triG[t]);
            if (tid < 16) keptW[tid] = 0;
            __syncthreads();

            if (tid < 64 && n > 0) {
                u64 fut = 0;
                if (lane < W) {
                    int cnt = n - (lane << 6);
                    fut = (cnt >= 64) ? ~0ULL : ((1ULL << cnt) - 1);
                }
                unsigned curLo, curHi;
                {
                    u64 c0 = (n >= 64) ? ~0ULL : ((1ULL << n) - 1);
                    curLo = (unsigned)__builtin_amdgcn_readfirstlane((int)(unsigned)c0);
                    curHi = (unsigned)__builtin_amdgcn_readfirstlane((int)(unsigned)(c0 >> 32));
                }
                int cw = 0;
                for (;;) {
                    int base = 64 * (cw * W - (cw * (cw - 1)) / 2);
                    int Wa = W - cw;
                    unsigned rdLo = 0, rdHi = 0;
                    {
                        int r = (cw << 6) + lane;
                        if (r < n) {
                            u64 v = buf[base + lane * Wa];
                            rdLo = (unsigned)v; rdHi = (unsigned)(v >> 32);
                        }
                    }
                    unsigned khLo = 0, khHi = 0;
                    while (curLo | curHi) {
                        int b = curLo ? __builtin_ctz(curLo) : (32 + __builtin_ctz(curHi));
                        unsigned wLo = (unsigned)__builtin_amdgcn_readlane((int)rdLo, b);
                        unsigned wHi = (unsigned)__builtin_amdgcn_readlane((int)rdHi, b);
                        if (curLo) { khLo |= curLo & (0u - curLo); curLo &= curLo - 1; }
                        else       { khHi |= curHi & (0u - curHi); curHi &= curHi - 1; }
                        curLo &= ~wLo; curHi &= ~wHi;
                    }
                    if (lane == 0) keptW[cw] = ((u64)khHi << 32) | khLo;
                    {
                        bool act = (lane > cw) && (lane < W);
                        int off0 = base + (lane - cw);
                        unsigned kl = khLo, kh = khHi;
                        while (kl | kh) {
                            int b = kl ? __builtin_ctz(kl) : (32 + __builtin_ctz(kh));
                            if (kl) kl &= kl - 1; else kh &= kh - 1;
                            if (act) fut &= ~buf[off0 + b * Wa];
                        }
                    }
                    u64 m = __ballot((fut != 0) && (lane > cw));
                    if (!m) break;
                    int ncw = (int)__builtin_ctzll(m);
                    curLo = (unsigned)__builtin_amdgcn_readlane((int)(unsigned)fut, ncw);
                    curHi = (unsigned)__builtin_amdgcn_readlane((int)(unsigned)(fut >> 32), ncw);
                    cw = ncw;
                }
            }
            __syncthreads();

            if (tid < n && ((keptW[tid >> 6] >> (tid & 63)) & 1ULL)) {
                u64 key = aload(&sKeysG[tid]);
                unsigned u = ~(unsigned)(key >> 32);
                float score = __uint_as_float(u ^ 0x80000000u);
                int x1, y1, x2, y2; unpackBox(aload(&sBoxPk[tid]), x1, y1, x2, y2);
                out[5*tid+0] = score;
                out[5*tid+1] = (float)x1;
                out[5*tid+2] = (float)y1;
                out[5*tid+3] = (float)(x2 - x1);
                out[5*tid+4] = (float)(y2 - y1);
            }
        }
    } else {
        // ===== correctness-only fallback (n > NFAST; never expected) =====
        gbar(b1s);
        gbar(b2s);
        if (bid != 0) return;
        for (int p = tid; p < n; p += 1024) {
            u64 kp = aload(&wsKeysPk[p]);
            int rank = 0;
            for (int q = 0; q < n; ++q) rank += (aload(&wsKeysPk[q]) < kp) ? 1 : 0;
            fbKey[rank] = kp;
            fbBox[rank] = aload(&wsBoxPk[(unsigned)kp]);
        }
        __syncthreads();
        if (tid < 64) {
            int kc = 0;
            for (int base2 = 0; base2 < n; base2 += 64) {
                int p = base2 + lane;
                bool in = p < n;
                u64 bp = in ? fbBox[p] : 0, kp2 = in ? fbKey[p] : 0;
                int x1, y1, x2, y2; unpackBox(bp, x1, y1, x2, y2);
                int ar = __mul24(x2 - x1, y2 - y1);
                bool dead = !in;
                for (int k = 0; k < kc; ++k) {
                    int kx1, ky1, kx2, ky2; unpackBox(kArr[k], kx1, ky1, kx2, ky2);
                    int kar = __mul24(kx2 - kx1, ky2 - ky1);
                    int iw = max(min(x2, kx2) - max(x1, kx1), 0);
                    int ih = max(min(y2, ky2) - max(y1, ky1), 0);
                    int I = __mul24(iw, ih); int P = ar + kar;
                    if (I < P && 3 * I > P) dead = true;
                }
                u64 scan = __ballot(!dead);
                while (scan) {
                    int t = (int)__builtin_ctzll(scan);
                    scan &= scan - 1;
                    u64 tb = __shfl(bp, t);
                    if (lane == t) {
                        kArr[kc] = bp;
                        unsigned u = ~(unsigned)(kp2 >> 32);
                        float score = __uint_as_float(u ^ 0x80000000u);
                        out[5*p+0] = score;
                        out[5*p+1] = (float)x1; out[5*p+2] = (float)y1;
                        out[5*p+3] = (float)(x2 - x1); out[5*p+4] = (float)(y2 - y1);
                    }
                    kc++;
                    bool kill = false;
                    if (!dead && lane > t) {
                        int tx1, ty1, tx2, ty2; unpackBox(tb, tx1, ty1, tx2, ty2);
                        int tar = __mul24(tx2 - tx1, ty2 - ty1);
                        int iw = max(min(x2, tx2) - max(x1, tx1), 0);
                        int ih = max(min(y2, ty2) - max(y1, ty1), 0);
                        int I = __mul24(iw, ih); int P = ar + tar;
                        kill = (I < P) && (3 * I > P);
                    }
                    dead = dead || kill;
                    scan &= ~__ballot(dead);
                }
            }
        }
    }
}

extern "C" void kernel_launch(void* const* d_in, const int* in_sizes, int n_in,
                              void* d_out, int out_size, void* d_ws, size_t ws_size,
                              hipStream_t stream) {
    const float* outs0 = (const float*)d_in[0];
    const float* outs1 = (const float*)d_in[1];
    float* out = (float*)d_out;
    char* ws = (char*)d_ws;
    size_t o = 0;
    unsigned* ctrl = (unsigned*)(ws + o); o += 512;
    u64* wsKeysPk  = (u64*)(ws + o); o += (size_t)8192 * 8;   // 64 KB
    u64* wsBoxPk   = (u64*)(ws + o); o += (size_t)8192 * 8;   // 64 KB
    u64* sKeysG    = (u64*)(ws + o); o += (size_t)1024 * 8;   // 8 KB
    u64* sBoxPk    = (u64*)(ws + o); o += (size_t)1024 * 8;   // 8 KB
    u64* triG      = (u64*)(ws + o); o += (size_t)6720 * 8;   // 52.5 KB
    u64* fbKey     = (u64*)(ws + o); o += (size_t)8192 * 8;   // 64 KB (fallback)
    u64* fbBox     = (u64*)(ws + o); o += (size_t)8192 * 8;   // 64 KB (fallback)
    u64* kArr      = (u64*)(ws + o); o += (size_t)8192 * 8;   // 64 KB (fallback)

    hipLaunchKernelGGL(k_all, dim3(NB), dim3(1024), 0, stream,
                       outs0, outs1, out, ctrl, wsKeysPk, wsBoxPk,
                       sKeysG, sBoxPk, triG, fbKey, fbBox, kArr);
}